// Round 11
// baseline (219.373 us; speedup 1.0000x reference)
//
#include <hip/hip_runtime.h>

#define N_TOK 2048
#define DD 512
#define FF 512
#define EE 64
#define TK 6
#define NG 66
#define RSLOT 12288   // N_TOK*TK
#define NSLOT 16384   // RSLOT + 2*N_TOK
#define BM 64
#define BN 64
#define BK 64
#define NKT 8         // 512/64
#define MAXT 320
#define MATSZ 262144  // 512*512

typedef float f32x4 __attribute__((ext_vector_type(4)));
typedef __bf16 bf16x8 __attribute__((ext_vector_type(8)));

__device__ __forceinline__ unsigned cvtpk(float lo, float hi) {
  unsigned r;
  asm("v_cvt_pk_bf16_f32 %0, %1, %2" : "=v"(r) : "v"(lo), "v"(hi));
  return r;
}

// async global->LDS DMA, 16B/lane; dest = wave-uniform base + lane*16
__device__ __forceinline__ void gll16(const void* g, void* l) {
  __builtin_amdgcn_global_load_lds(
      (const __attribute__((address_space(1))) unsigned int*)g,
      (__attribute__((address_space(3))) unsigned int*)l, 16, 0, 0);
}

// ------- convert+transpose weights, LDS-free, asm-forced 16-deep load pipeline.
// r9/r10: compiler recycled load dest regs (VGPR 40-52), capping in-flight at ~8
// -> 2.2 TB/s latency-bound. Volatile asm loads + single vmcnt(0) forces all 16
// destinations live (AITER pattern).
__global__ __launch_bounds__(256) void convw_k(
    const float* __restrict__ Wg, const float* __restrict__ Wu, const float* __restrict__ Wd,
    const float* __restrict__ sWg, const float* __restrict__ sWu, const float* __restrict__ sWd,
    short* __restrict__ Wt) {
  int y = blockIdx.y;
  int kind = y / 66, idx = y % 66;
  const float* src;
  if (kind == 0)      src = (idx < EE) ? Wg + (size_t)idx * MATSZ : sWg + (size_t)(idx - EE) * MATSZ;
  else if (kind == 1) src = (idx < EE) ? Wu + (size_t)idx * MATSZ : sWu + (size_t)(idx - EE) * MATSZ;
  else                src = (idx < EE) ? Wd + (size_t)idx * MATSZ : sWd + (size_t)(idx - EE) * MATSZ;
  short* dst = Wt + (size_t)y * MATSZ;
  int f0 = (blockIdx.x & 7) * 64;
  int dh = (blockIdx.x >> 3) * 256;
  int lane = threadIdx.x & 63, w = threadIdx.x >> 6;
  int fl = lane & 15, dg = lane >> 4;
  const float* sp = src + (size_t)(dh + dg * 8) * 512 + f0 + fl * 4;
  short* dp = dst + (size_t)(f0 + fl * 4) * 512 + dh + dg * 8;

  f32x4 v00, v01, v02, v03, v04, v05, v06, v07;
  f32x4 v10, v11, v12, v13, v14, v15, v16, v17;
#define LDV(dst_, it, jd) \
  asm volatile("global_load_dwordx4 %0, %1, off" \
               : "=v"(dst_) : "v"(sp + (size_t)(((it) * 4 + w) * 32 + (jd)) * 512))
  LDV(v00, 0, 0); LDV(v01, 0, 1); LDV(v02, 0, 2); LDV(v03, 0, 3);
  LDV(v04, 0, 4); LDV(v05, 0, 5); LDV(v06, 0, 6); LDV(v07, 0, 7);
  LDV(v10, 1, 0); LDV(v11, 1, 1); LDV(v12, 1, 2); LDV(v13, 1, 3);
  LDV(v14, 1, 4); LDV(v15, 1, 5); LDV(v16, 1, 6); LDV(v17, 1, 7);
#undef LDV
  asm volatile("s_waitcnt vmcnt(0)" ::: "memory");
  __builtin_amdgcn_sched_barrier(0);

#define STV(it, a0, a1, a2, a3, a4, a5, a6, a7) do { \
    int db = ((it) * 4 + w) * 32; \
    _Pragma("unroll") \
    for (int jf = 0; jf < 4; ++jf) { \
      uint4 o; \
      o.x = cvtpk(a0[jf], a1[jf]); \
      o.y = cvtpk(a2[jf], a3[jf]); \
      o.z = cvtpk(a4[jf], a5[jf]); \
      o.w = cvtpk(a6[jf], a7[jf]); \
      *(uint4*)(dp + (size_t)jf * 512 + db) = o; \
    } \
  } while (0)
  STV(0, v00, v01, v02, v03, v04, v05, v06, v07);
  STV(1, v10, v11, v12, v13, v14, v15, v16, v17);
#undef STV
}

// ------- convert X f32 -> bf16
__global__ void convx_k(const float* __restrict__ x, short* __restrict__ Xb) {
  int i = blockIdx.x * 256 + threadIdx.x;
  const f32x4* p = (const f32x4*)(x + (size_t)i * 8);
  f32x4 v0 = p[0], v1 = p[1];
  uint4 o;
  o.x = cvtpk(v0[0], v0[1]); o.y = cvtpk(v0[2], v0[3]);
  o.z = cvtpk(v1[0], v1[1]); o.w = cvtpk(v1[2], v1[3]);
  *(uint4*)&Xb[(size_t)i * 8] = o;
}

// ---------------- router ----------------
__global__ __launch_bounds__(256) void router_k(
    const float* __restrict__ x, const float* __restrict__ Wr,
    int* __restrict__ top_i, float* __restrict__ top_w, int* __restrict__ cnt) {
  __shared__ float xs[16 * 512];
  __shared__ float part[4][16][64];
  int tid = threadIdx.x, lane = tid & 63, w = tid >> 6;
  int t0 = blockIdx.x * 16;
  const f32x4* xin = (const f32x4*)(x + (size_t)t0 * DD);
  f32x4* xs4 = (f32x4*)xs;
#pragma unroll
  for (int i = 0; i < 8; ++i) xs4[i * 256 + tid] = xin[i * 256 + tid];
  __syncthreads();
  float acc[16];
#pragma unroll
  for (int t = 0; t < 16; ++t) acc[t] = 0.f;
  for (int kk = 0; kk < 32; ++kk) {
    int k = w * 128 + kk * 4;
    float w0 = Wr[(size_t)(k + 0) * EE + lane];
    float w1 = Wr[(size_t)(k + 1) * EE + lane];
    float w2 = Wr[(size_t)(k + 2) * EE + lane];
    float w3 = Wr[(size_t)(k + 3) * EE + lane];
#pragma unroll
    for (int t = 0; t < 16; ++t) {
      f32x4 xv = *(const f32x4*)&xs[t * 512 + k];
      acc[t] = fmaf(xv[0], w0, acc[t]);
      acc[t] = fmaf(xv[1], w1, acc[t]);
      acc[t] = fmaf(xv[2], w2, acc[t]);
      acc[t] = fmaf(xv[3], w3, acc[t]);
    }
  }
#pragma unroll
  for (int t = 0; t < 16; ++t) part[w][t][lane] = acc[t];
  __syncthreads();
#pragma unroll
  for (int tt = 0; tt < 4; ++tt) {
    int t = w * 4 + tt;
    float l0 = part[0][t][lane] + part[1][t][lane] + part[2][t][lane] + part[3][t][lane];
    float m = l0;
#pragma unroll
    for (int s = 32; s; s >>= 1) m = fmaxf(m, __shfl_xor(m, s));
    float p = __expf(l0 - m);
    int wi[TK]; float wv[TK];
#pragma unroll
    for (int it = 0; it < TK; ++it) {
      float v = p;
#pragma unroll
      for (int s = 32; s; s >>= 1) v = fmaxf(v, __shfl_xor(v, s));
      unsigned long long b = __ballot(p == v);
      int idx = __ffsll((unsigned long long)b) - 1;
      wi[it] = idx; wv[it] = v;
      if (lane == idx) p = -1.f;
    }
    float wsum = 0.f;
#pragma unroll
    for (int it = 0; it < TK; ++it) wsum += wv[it];
    int tg = t0 + t;
    if (lane < TK) {
      int si = 0; float sv = 0.f;
#pragma unroll
      for (int it = 0; it < TK; ++it) if (lane == it) { si = wi[it]; sv = wv[it]; }
      top_i[tg * TK + lane] = si;
      top_w[tg * TK + lane] = sv / wsum;
      atomicAdd(&cnt[si], 1);
    }
  }
}

// ---------------- offsets + dense work list ----------------
__global__ void offsets_k(const int* __restrict__ cnt, int* __restrict__ goff,
                          int* __restrict__ fill, int* __restrict__ wk_g,
                          int* __restrict__ wk_mt, int* __restrict__ nitems) {
  int i = threadIdx.x;  // 0..63
  fill[i] = 0;
  int c = cnt[i];
  int s = c;
#pragma unroll
  for (int d = 1; d < 64; d <<= 1) { int t = __shfl_up(s, d); if (i >= d) s += t; }
  goff[i] = s - c;
  if (i == 63) {
    goff[EE] = RSLOT;
    goff[EE + 1] = RSLOT + N_TOK;
    goff[EE + 2] = RSLOT + 2 * N_TOK;
  }
  int nt = (c + BM - 1) >> 6;
  int ts = nt;
#pragma unroll
  for (int d = 1; d < 64; d <<= 1) { int t = __shfl_up(ts, d); if (i >= d) ts += t; }
  int texcl = ts - nt;
  for (int t = 0; t < nt; ++t) { wk_g[texcl + t] = i; wk_mt[texcl + t] = t; }
  int tot = __shfl(ts, 63);
  wk_g[tot + i] = EE + (i >> 5);
  wk_mt[tot + i] = i & 31;
  if (i == 0) nitems[0] = tot + 64;
}

// ---------------- scatter (also builds token->slot inverse map) ----------------
__global__ void scatter_k(const int* __restrict__ top_i, const float* __restrict__ top_w,
                          const int* __restrict__ goff, int* __restrict__ fill,
                          int* __restrict__ btok, float* __restrict__ bw,
                          int* __restrict__ tslot) {
  int idx = blockIdx.x * blockDim.x + threadIdx.x;
  if (idx < RSLOT) {
    int e = top_i[idx];
    int pos = goff[e] + atomicAdd(&fill[e], 1);
    btok[pos] = idx / TK;
    bw[pos] = top_w[idx];
    tslot[idx] = pos;
  } else if (idx < NSLOT) {
    int j = idx - RSLOT;
    btok[idx] = j & (N_TOK - 1);
    bw[idx] = 1.0f;
  }
}

// ---------------- GEMM1: H = silu(Xb*Wg) * (Xb*Wu), all-bf16, gll16 staged ----
__global__ __launch_bounds__(256) void gemm1_k(
    const short* __restrict__ Xb, const short* __restrict__ Wtg, const short* __restrict__ Wtu,
    const int* __restrict__ goff, const int* __restrict__ btok,
    const int* __restrict__ wk_g, const int* __restrict__ wk_mt,
    const int* __restrict__ nitems, short* __restrict__ H) {
  int item = blockIdx.y;
  if (item >= nitems[0]) return;
  int g = wk_g[item], mt = wk_mt[item];
  int s0g = goff[g], cnt = goff[g + 1] - s0g;
  int n0 = blockIdx.x * BN;
  const short* gmat = Wtg + (size_t)g * MATSZ;
  const short* umat = Wtu + (size_t)g * MATSZ;

  __shared__ __align__(16) short lds[2][12288];   // 48 KB

  int tid = threadIdx.x, lane = tid & 63, w = tid >> 6;
  int wr = w >> 1, wc = w & 1;
  int lr = lane & 15, lgq = lane >> 4;
  int s0 = s0g + mt * BM;

  const short* sp[6];
  int ldst[6];
#pragma unroll
  for (int q = 0; q < 6; ++q) {
    int c = w * 6 + q;
    ldst[q] = c * 512;
    int rl = (c & 7) * 8 + (lane >> 3);
    int u = (lane & 7) ^ (rl & 7);
    if (c < 8) {
      int slot = (mt * BM + rl < cnt) ? s0 + rl : s0;
      sp[q] = Xb + (size_t)btok[slot] * 512 + u * 8;
    } else if (c < 16) {
      sp[q] = gmat + (size_t)(n0 + rl) * 512 + u * 8;
    } else {
      sp[q] = umat + (size_t)(n0 + rl) * 512 + u * 8;
    }
  }

  f32x4 accg[2][2], accu[2][2];
#pragma unroll
  for (int i = 0; i < 2; ++i)
#pragma unroll
    for (int j = 0; j < 2; ++j) {
      accg[i][j] = f32x4{0.f, 0.f, 0.f, 0.f};
      accu[i][j] = f32x4{0.f, 0.f, 0.f, 0.f};
    }

  auto STAGE = [&](int b, int kt) {
#pragma unroll
    for (int q = 0; q < 6; ++q) gll16(sp[q] + kt * 64, &lds[b][ldst[q]]);
  };
  auto COMPUTE = [&](int b) {
    const short* L = lds[b];
#pragma unroll
    for (int ks = 0; ks < 2; ++ks) {
      bf16x8 af[2], bg[2], bu[2];
#pragma unroll
      for (int i = 0; i < 2; ++i) {
        int row = wr * 32 + i * 16 + lr;
        af[i] = *(const bf16x8*)&L[row * 64 + (((ks * 4 + lgq) ^ (row & 7)) * 8)];
      }
#pragma unroll
      for (int j = 0; j < 2; ++j) {
        int fr = wc * 32 + j * 16 + lr;
        int o = fr * 64 + (((ks * 4 + lgq) ^ (fr & 7)) * 8);
        bg[j] = *(const bf16x8*)&L[4096 + o];
        bu[j] = *(const bf16x8*)&L[8192 + o];
      }
#pragma unroll
      for (int i = 0; i < 2; ++i)
#pragma unroll
        for (int j = 0; j < 2; ++j) {
          accg[i][j] = __builtin_amdgcn_mfma_f32_16x16x32_bf16(af[i], bg[j], accg[i][j], 0, 0, 0);
          accu[i][j] = __builtin_amdgcn_mfma_f32_16x16x32_bf16(af[i], bu[j], accu[i][j], 0, 0, 0);
        }
    }
  };

  STAGE(0, 0);
  __syncthreads();
  int b = 0;
#pragma unroll 1
  for (int kt = 0; kt < NKT; ++kt) {
    if (kt + 1 < NKT) STAGE(b ^ 1, kt + 1);
    COMPUTE(b);
    __syncthreads();
    b ^= 1;
  }

#pragma unroll
  for (int i = 0; i < 2; ++i)
#pragma unroll
    for (int j = 0; j < 2; ++j)
#pragma unroll
      for (int r = 0; r < 4; ++r) {
        int mrow = wr * 32 + i * 16 + lgq * 4 + r;
        if (mt * BM + mrow < cnt) {
          float gg = accg[i][j][r];
          float uu = accu[i][j][r];
          float hv = (gg / (1.f + __expf(-gg))) * uu;
          int col = n0 + wc * 32 + j * 16 + lr;
          H[(size_t)(s0 + mrow) * FF + col] = (short)(cvtpk(hv, hv) & 0xffffu);
        }
      }
}

// ---------------- GEMM2: Osl[slot] = bw[slot] * (H[slot] x Wtd_g)  (no atomics) --
__global__ __launch_bounds__(256) void gemm2_k(
    const short* __restrict__ H, const short* __restrict__ Wtd,
    const int* __restrict__ goff, const float* __restrict__ bw,
    const int* __restrict__ wk_g, const int* __restrict__ wk_mt,
    const int* __restrict__ nitems, short* __restrict__ Osl) {
  int item = blockIdx.y;
  if (item >= nitems[0]) return;
  int g = wk_g[item], mt = wk_mt[item];
  int s0g = goff[g], cnt = goff[g + 1] - s0g;
  int n0 = blockIdx.x * BN;
  const short* dmat = Wtd + (size_t)g * MATSZ;

  __shared__ __align__(16) short lds[2][8192];    // 32 KB

  int tid = threadIdx.x, lane = tid & 63, w = tid >> 6;
  int wr = w >> 1, wc = w & 1;
  int lr = lane & 15, lgq = lane >> 4;
  int s0 = s0g + mt * BM;

  const short* sp[4];
  int ldst[4];
#pragma unroll
  for (int q = 0; q < 4; ++q) {
    int c = w * 4 + q;
    ldst[q] = c * 512;
    int rl = (c & 7) * 8 + (lane >> 3);
    int u = (lane & 7) ^ (rl & 7);
    if (c < 8) {
      int slot = (mt * BM + rl < cnt) ? s0 + rl : s0;
      sp[q] = H + (size_t)slot * 512 + u * 8;
    } else {
      sp[q] = dmat + (size_t)(n0 + rl) * 512 + u * 8;
    }
  }

  f32x4 acc[2][2];
#pragma unroll
  for (int i = 0; i < 2; ++i)
#pragma unroll
    for (int j = 0; j < 2; ++j) acc[i][j] = f32x4{0.f, 0.f, 0.f, 0.f};

  auto STAGE = [&](int b, int kt) {
#pragma unroll
    for (int q = 0; q < 4; ++q) gll16(sp[q] + kt * 64, &lds[b][ldst[q]]);
  };
  auto COMPUTE = [&](int b) {
    const short* L = lds[b];
#pragma unroll
    for (int ks = 0; ks < 2; ++ks) {
      bf16x8 af[2], bd[2];
#pragma unroll
      for (int i = 0; i < 2; ++i) {
        int row = wr * 32 + i * 16 + lr;
        af[i] = *(const bf16x8*)&L[row * 64 + (((ks * 4 + lgq) ^ (row & 7)) * 8)];
      }
#pragma unroll
      for (int j = 0; j < 2; ++j) {
        int dr = wc * 32 + j * 16 + lr;
        bd[j] = *(const bf16x8*)&L[4096 + dr * 64 + (((ks * 4 + lgq) ^ (dr & 7)) * 8)];
      }
#pragma unroll
      for (int i = 0; i < 2; ++i)
#pragma unroll
        for (int j = 0; j < 2; ++j)
          acc[i][j] = __builtin_amdgcn_mfma_f32_16x16x32_bf16(af[i], bd[j], acc[i][j], 0, 0, 0);
    }
  };

  STAGE(0, 0);
  __syncthreads();
  int b = 0;
#pragma unroll 1
  for (int kt = 0; kt < NKT; ++kt) {
    if (kt + 1 < NKT) STAGE(b ^ 1, kt + 1);
    COMPUTE(b);
    __syncthreads();
    b ^= 1;
  }

#pragma unroll
  for (int i = 0; i < 2; ++i)
#pragma unroll
    for (int r = 0; r < 4; ++r) {
      int mrow = wr * 32 + i * 16 + lgq * 4 + r;
      if (mt * BM + mrow < cnt) {
        int slot = s0 + mrow;
        float wv = bw[slot];
#pragma unroll
        for (int j = 0; j < 2; ++j) {
          int col = n0 + wc * 32 + j * 16 + lr;
          Osl[(size_t)slot * DD + col] = (short)(cvtpk(acc[i][j][r] * wv, 0.f) & 0xffffu);
        }
      }
    }
}

// ---------------- combine: out[t] = x[t] + sum over 6 routed + 2 shared slots ----
__global__ __launch_bounds__(256) void combine_k(
    const short* __restrict__ Osl, const float* __restrict__ x,
    const int* __restrict__ tslot, float* __restrict__ out) {
  int wv = threadIdx.x >> 6, lane = threadIdx.x & 63;
  int t = blockIdx.x * 4 + wv;
  int d0 = lane * 8;
  const float* xp = x + (size_t)t * DD + d0;
  f32x4 sa = *(const f32x4*)xp;
  f32x4 sb = *(const f32x4*)(xp + 4);
  int slots[8];
#pragma unroll
  for (int k = 0; k < 6; ++k) slots[k] = tslot[t * TK + k];
  slots[6] = RSLOT + t;
  slots[7] = RSLOT + N_TOK + t;
#pragma unroll
  for (int k = 0; k < 8; ++k) {
    uint4 hv = *(const uint4*)&Osl[(size_t)slots[k] * DD + d0];
    unsigned u[4] = {hv.x, hv.y, hv.z, hv.w};
#pragma unroll
    for (int q = 0; q < 4; ++q) {
      float lo = __builtin_bit_cast(float, u[q] << 16);
      float hi = __builtin_bit_cast(float, u[q] & 0xffff0000u);
      if (q < 2) { sa[q * 2] += lo; sa[q * 2 + 1] += hi; }
      else { sb[(q - 2) * 2] += lo; sb[(q - 2) * 2 + 1] += hi; }
    }
  }
  float* op = out + (size_t)t * DD + d0;
  *(f32x4*)op = sa;
  *(f32x4*)(op + 4) = sb;
}

extern "C" void kernel_launch(void* const* d_in, const int* in_sizes, int n_in,
                              void* d_out, int out_size, void* d_ws, size_t ws_size,
                              hipStream_t stream) {
  const float* x   = (const float*)d_in[0];
  const float* Wr  = (const float*)d_in[1];
  const float* sWg = (const float*)d_in[2];
  const float* sWu = (const float*)d_in[3];
  const float* sWd = (const float*)d_in[4];
  const float* Wg  = (const float*)d_in[5];
  const float* Wu  = (const float*)d_in[6];
  const float* Wd  = (const float*)d_in[7];
  float* out = (float*)d_out;

  char* wsb = (char*)d_ws;
  size_t off = 0;
  short* Wt = (short*)(wsb + off);    off += (size_t)198 * MATSZ * 2;   // 99 MB bf16
  short* H  = (short*)(wsb + off);    off += (size_t)NSLOT * FF * 2;    // 16 MB
  short* Osl = (short*)(wsb + off);   off += (size_t)NSLOT * DD * 2;    // 16 MB
  short* Xb = (short*)(wsb + off);    off += (size_t)N_TOK * DD * 2;    // 2 MB
  int*   top_i = (int*)(wsb + off);   off += (size_t)RSLOT * 4;
  float* top_w = (float*)(wsb + off); off += (size_t)RSLOT * 4;
  int*   btok = (int*)(wsb + off);    off += (size_t)NSLOT * 4;
  float* bwt  = (float*)(wsb + off);  off += (size_t)NSLOT * 4;
  int*   tslot = (int*)(wsb + off);   off += (size_t)RSLOT * 4;
  int*   cnt  = (int*)(wsb + off);    off += 256;
  int*   fill = (int*)(wsb + off);    off += 256;
  int*   goff = (int*)(wsb + off);    off += 512;
  int*   wk_g = (int*)(wsb + off);    off += MAXT * 4;
  int*   wk_mt = (int*)(wsb + off);   off += MAXT * 4;
  int*   nitems = (int*)(wsb + off);  off += 256;

  const short* Wtg = Wt;
  const short* Wtu = Wt + (size_t)66 * MATSZ;
  const short* Wtd = Wt + (size_t)132 * MATSZ;

  hipMemsetAsync(cnt, 0, 256, stream);
  convw_k<<<dim3(16, 198), 256, 0, stream>>>(Wg, Wu, Wd, sWg, sWu, sWd, Wt);
  convx_k<<<512, 256, 0, stream>>>(x, Xb);
  router_k<<<N_TOK / 16, 256, 0, stream>>>(x, Wr, top_i, top_w, cnt);
  offsets_k<<<1, 64, 0, stream>>>(cnt, goff, fill, wk_g, wk_mt, nitems);
  scatter_k<<<NSLOT / 256, 256, 0, stream>>>(top_i, top_w, goff, fill, btok, bwt, tslot);
  dim3 grid1(FF / BN, MAXT, 1);
  gemm1_k<<<grid1, 256, 0, stream>>>(Xb, Wtg, Wtu, goff, btok, wk_g, wk_mt, nitems, H);
  dim3 grid2(DD / BN, MAXT, 1);
  gemm2_k<<<grid2, 256, 0, stream>>>(H, Wtd, goff, bwt, wk_g, wk_mt, nitems, Osl);
  combine_k<<<N_TOK / 4, 256, 0, stream>>>(Osl, x, tslot, out);
}

// Round 12
// 214.815 us; speedup vs baseline: 1.0212x; 1.0212x over previous
//
#include <hip/hip_runtime.h>

#define N_TOK 2048
#define DD 512
#define FF 512
#define EE 64
#define TK 6
#define NG 66
#define RSLOT 12288   // N_TOK*TK
#define NSLOT 16384   // RSLOT + 2*N_TOK
#define BM 64
#define BN 64
#define BK 64
#define NKT 8         // 512/64
#define MAXT 320
#define MATSZ 262144  // 512*512

typedef float f32x4 __attribute__((ext_vector_type(4)));
typedef __bf16 bf16x8 __attribute__((ext_vector_type(8)));

__device__ __forceinline__ unsigned cvtpk(float lo, float hi) {
  unsigned r;
  asm("v_cvt_pk_bf16_f32 %0, %1, %2" : "=v"(r) : "v"(lo), "v"(hi));
  return r;
}

// async global->LDS DMA, 16B/lane; dest = wave-uniform base + lane*16
__device__ __forceinline__ void gll16(const void* g, void* l) {
  __builtin_amdgcn_global_load_lds(
      (const __attribute__((address_space(1))) unsigned int*)g,
      (__attribute__((address_space(3))) unsigned int*)l, 16, 0, 0);
}

// ------- convert+transpose weights via LDS, TLP-streaming design.
// Tile [64d][32f] f32, LDS pad 33 (both phases exactly 2-way banks = free).
// Reads: 128B contiguous per d-row. Writes: 128B contiguous per f-row.
// 25344 tiny blocks -> ~8 blocks/CU resident -> latency hidden by TLP.
__global__ __launch_bounds__(256) void convw_k(
    const float* __restrict__ Wg, const float* __restrict__ Wu, const float* __restrict__ Wd,
    const float* __restrict__ sWg, const float* __restrict__ sWu, const float* __restrict__ sWd,
    short* __restrict__ Wt) {
  __shared__ float T[64][33];
  int y = blockIdx.y;
  int kind = y / 66, idx = y % 66;
  const float* src;
  if (kind == 0)      src = (idx < EE) ? Wg + (size_t)idx * MATSZ : sWg + (size_t)(idx - EE) * MATSZ;
  else if (kind == 1) src = (idx < EE) ? Wu + (size_t)idx * MATSZ : sWu + (size_t)(idx - EE) * MATSZ;
  else                src = (idx < EE) ? Wd + (size_t)idx * MATSZ : sWd + (size_t)(idx - EE) * MATSZ;
  short* dst = Wt + (size_t)y * MATSZ;
  int d0 = (blockIdx.x & 7) * 64;
  int f0 = (blockIdx.x >> 3) * 32;
  int t = threadIdx.x;

  int r = t >> 3, fo = (t & 7) * 4;
  const float* sp = src + (size_t)(d0 + r) * 512 + f0 + fo;
  *(f32x4*)&T[r][fo]      = *(const f32x4*)sp;
  *(f32x4*)&T[r + 32][fo] = *(const f32x4*)(sp + (size_t)32 * 512);
  __syncthreads();

  int f = t >> 3, a = t & 7, dd = a * 8;
  float v[8];
#pragma unroll
  for (int i = 0; i < 8; ++i) v[i] = T[dd + i][f];
  uint4 o;
  o.x = cvtpk(v[0], v[1]); o.y = cvtpk(v[2], v[3]);
  o.z = cvtpk(v[4], v[5]); o.w = cvtpk(v[6], v[7]);
  *(uint4*)&dst[(size_t)(f0 + f) * 512 + d0 + dd] = o;
}

// ------- convert X f32 -> bf16
__global__ void convx_k(const float* __restrict__ x, short* __restrict__ Xb) {
  int i = blockIdx.x * 256 + threadIdx.x;
  const f32x4* p = (const f32x4*)(x + (size_t)i * 8);
  f32x4 v0 = p[0], v1 = p[1];
  uint4 o;
  o.x = cvtpk(v0[0], v0[1]); o.y = cvtpk(v0[2], v0[3]);
  o.z = cvtpk(v1[0], v1[1]); o.w = cvtpk(v1[2], v1[3]);
  *(uint4*)&Xb[(size_t)i * 8] = o;
}

// ---------------- router ----------------
__global__ __launch_bounds__(256) void router_k(
    const float* __restrict__ x, const float* __restrict__ Wr,
    int* __restrict__ top_i, float* __restrict__ top_w, int* __restrict__ cnt) {
  __shared__ float xs[16 * 512];
  __shared__ float part[4][16][64];
  int tid = threadIdx.x, lane = tid & 63, w = tid >> 6;
  int t0 = blockIdx.x * 16;
  const f32x4* xin = (const f32x4*)(x + (size_t)t0 * DD);
  f32x4* xs4 = (f32x4*)xs;
#pragma unroll
  for (int i = 0; i < 8; ++i) xs4[i * 256 + tid] = xin[i * 256 + tid];
  __syncthreads();
  float acc[16];
#pragma unroll
  for (int t = 0; t < 16; ++t) acc[t] = 0.f;
  for (int kk = 0; kk < 32; ++kk) {
    int k = w * 128 + kk * 4;
    float w0 = Wr[(size_t)(k + 0) * EE + lane];
    float w1 = Wr[(size_t)(k + 1) * EE + lane];
    float w2 = Wr[(size_t)(k + 2) * EE + lane];
    float w3 = Wr[(size_t)(k + 3) * EE + lane];
#pragma unroll
    for (int t = 0; t < 16; ++t) {
      f32x4 xv = *(const f32x4*)&xs[t * 512 + k];
      acc[t] = fmaf(xv[0], w0, acc[t]);
      acc[t] = fmaf(xv[1], w1, acc[t]);
      acc[t] = fmaf(xv[2], w2, acc[t]);
      acc[t] = fmaf(xv[3], w3, acc[t]);
    }
  }
#pragma unroll
  for (int t = 0; t < 16; ++t) part[w][t][lane] = acc[t];
  __syncthreads();
#pragma unroll
  for (int tt = 0; tt < 4; ++tt) {
    int t = w * 4 + tt;
    float l0 = part[0][t][lane] + part[1][t][lane] + part[2][t][lane] + part[3][t][lane];
    float m = l0;
#pragma unroll
    for (int s = 32; s; s >>= 1) m = fmaxf(m, __shfl_xor(m, s));
    float p = __expf(l0 - m);
    int wi[TK]; float wv[TK];
#pragma unroll
    for (int it = 0; it < TK; ++it) {
      float v = p;
#pragma unroll
      for (int s = 32; s; s >>= 1) v = fmaxf(v, __shfl_xor(v, s));
      unsigned long long b = __ballot(p == v);
      int idx = __ffsll((unsigned long long)b) - 1;
      wi[it] = idx; wv[it] = v;
      if (lane == idx) p = -1.f;
    }
    float wsum = 0.f;
#pragma unroll
    for (int it = 0; it < TK; ++it) wsum += wv[it];
    int tg = t0 + t;
    if (lane < TK) {
      int si = 0; float sv = 0.f;
#pragma unroll
      for (int it = 0; it < TK; ++it) if (lane == it) { si = wi[it]; sv = wv[it]; }
      top_i[tg * TK + lane] = si;
      top_w[tg * TK + lane] = sv / wsum;
      atomicAdd(&cnt[si], 1);
    }
  }
}

// ---------------- offsets + dense work list ----------------
__global__ void offsets_k(const int* __restrict__ cnt, int* __restrict__ goff,
                          int* __restrict__ fill, int* __restrict__ wk_g,
                          int* __restrict__ wk_mt, int* __restrict__ nitems) {
  int i = threadIdx.x;  // 0..63
  fill[i] = 0;
  int c = cnt[i];
  int s = c;
#pragma unroll
  for (int d = 1; d < 64; d <<= 1) { int t = __shfl_up(s, d); if (i >= d) s += t; }
  goff[i] = s - c;
  if (i == 63) {
    goff[EE] = RSLOT;
    goff[EE + 1] = RSLOT + N_TOK;
    goff[EE + 2] = RSLOT + 2 * N_TOK;
  }
  int nt = (c + BM - 1) >> 6;
  int ts = nt;
#pragma unroll
  for (int d = 1; d < 64; d <<= 1) { int t = __shfl_up(ts, d); if (i >= d) ts += t; }
  int texcl = ts - nt;
  for (int t = 0; t < nt; ++t) { wk_g[texcl + t] = i; wk_mt[texcl + t] = t; }
  int tot = __shfl(ts, 63);
  wk_g[tot + i] = EE + (i >> 5);
  wk_mt[tot + i] = i & 31;
  if (i == 0) nitems[0] = tot + 64;
}

// ---------------- scatter (also builds token->slot inverse map) ----------------
__global__ void scatter_k(const int* __restrict__ top_i, const float* __restrict__ top_w,
                          const int* __restrict__ goff, int* __restrict__ fill,
                          int* __restrict__ btok, float* __restrict__ bw,
                          int* __restrict__ tslot) {
  int idx = blockIdx.x * blockDim.x + threadIdx.x;
  if (idx < RSLOT) {
    int e = top_i[idx];
    int pos = goff[e] + atomicAdd(&fill[e], 1);
    btok[pos] = idx / TK;
    bw[pos] = top_w[idx];
    tslot[idx] = pos;
  } else if (idx < NSLOT) {
    int j = idx - RSLOT;
    btok[idx] = j & (N_TOK - 1);
    bw[idx] = 1.0f;
  }
}

// ---------------- GEMM1: H = silu(Xb*Wg) * (Xb*Wu), all-bf16, gll16 staged ----
__global__ __launch_bounds__(256) void gemm1_k(
    const short* __restrict__ Xb, const short* __restrict__ Wtg, const short* __restrict__ Wtu,
    const int* __restrict__ goff, const int* __restrict__ btok,
    const int* __restrict__ wk_g, const int* __restrict__ wk_mt,
    const int* __restrict__ nitems, short* __restrict__ H) {
  int item = blockIdx.y;
  if (item >= nitems[0]) return;
  int g = wk_g[item], mt = wk_mt[item];
  int s0g = goff[g], cnt = goff[g + 1] - s0g;
  int n0 = blockIdx.x * BN;
  const short* gmat = Wtg + (size_t)g * MATSZ;
  const short* umat = Wtu + (size_t)g * MATSZ;

  __shared__ __align__(16) short lds[2][12288];   // 48 KB

  int tid = threadIdx.x, lane = tid & 63, w = tid >> 6;
  int wr = w >> 1, wc = w & 1;
  int lr = lane & 15, lgq = lane >> 4;
  int s0 = s0g + mt * BM;

  const short* sp[6];
  int ldst[6];
#pragma unroll
  for (int q = 0; q < 6; ++q) {
    int c = w * 6 + q;
    ldst[q] = c * 512;
    int rl = (c & 7) * 8 + (lane >> 3);
    int u = (lane & 7) ^ (rl & 7);
    if (c < 8) {
      int slot = (mt * BM + rl < cnt) ? s0 + rl : s0;
      sp[q] = Xb + (size_t)btok[slot] * 512 + u * 8;
    } else if (c < 16) {
      sp[q] = gmat + (size_t)(n0 + rl) * 512 + u * 8;
    } else {
      sp[q] = umat + (size_t)(n0 + rl) * 512 + u * 8;
    }
  }

  f32x4 accg[2][2], accu[2][2];
#pragma unroll
  for (int i = 0; i < 2; ++i)
#pragma unroll
    for (int j = 0; j < 2; ++j) {
      accg[i][j] = f32x4{0.f, 0.f, 0.f, 0.f};
      accu[i][j] = f32x4{0.f, 0.f, 0.f, 0.f};
    }

  auto STAGE = [&](int b, int kt) {
#pragma unroll
    for (int q = 0; q < 6; ++q) gll16(sp[q] + kt * 64, &lds[b][ldst[q]]);
  };
  auto COMPUTE = [&](int b) {
    const short* L = lds[b];
#pragma unroll
    for (int ks = 0; ks < 2; ++ks) {
      bf16x8 af[2], bg[2], bu[2];
#pragma unroll
      for (int i = 0; i < 2; ++i) {
        int row = wr * 32 + i * 16 + lr;
        af[i] = *(const bf16x8*)&L[row * 64 + (((ks * 4 + lgq) ^ (row & 7)) * 8)];
      }
#pragma unroll
      for (int j = 0; j < 2; ++j) {
        int fr = wc * 32 + j * 16 + lr;
        int o = fr * 64 + (((ks * 4 + lgq) ^ (fr & 7)) * 8);
        bg[j] = *(const bf16x8*)&L[4096 + o];
        bu[j] = *(const bf16x8*)&L[8192 + o];
      }
#pragma unroll
      for (int i = 0; i < 2; ++i)
#pragma unroll
        for (int j = 0; j < 2; ++j) {
          accg[i][j] = __builtin_amdgcn_mfma_f32_16x16x32_bf16(af[i], bg[j], accg[i][j], 0, 0, 0);
          accu[i][j] = __builtin_amdgcn_mfma_f32_16x16x32_bf16(af[i], bu[j], accu[i][j], 0, 0, 0);
        }
    }
  };

  STAGE(0, 0);
  __syncthreads();
  int b = 0;
#pragma unroll 1
  for (int kt = 0; kt < NKT; ++kt) {
    if (kt + 1 < NKT) STAGE(b ^ 1, kt + 1);
    COMPUTE(b);
    __syncthreads();
    b ^= 1;
  }

#pragma unroll
  for (int i = 0; i < 2; ++i)
#pragma unroll
    for (int j = 0; j < 2; ++j)
#pragma unroll
      for (int r = 0; r < 4; ++r) {
        int mrow = wr * 32 + i * 16 + lgq * 4 + r;
        if (mt * BM + mrow < cnt) {
          float gg = accg[i][j][r];
          float uu = accu[i][j][r];
          float hv = (gg / (1.f + __expf(-gg))) * uu;
          int col = n0 + wc * 32 + j * 16 + lr;
          H[(size_t)(s0 + mrow) * FF + col] = (short)(cvtpk(hv, hv) & 0xffffu);
        }
      }
}

// ---------------- GEMM2: Osl[slot] = bw[slot] * (H[slot] x Wtd_g)  (no atomics) --
__global__ __launch_bounds__(256) void gemm2_k(
    const short* __restrict__ H, const short* __restrict__ Wtd,
    const int* __restrict__ goff, const float* __restrict__ bw,
    const int* __restrict__ wk_g, const int* __restrict__ wk_mt,
    const int* __restrict__ nitems, short* __restrict__ Osl) {
  int item = blockIdx.y;
  if (item >= nitems[0]) return;
  int g = wk_g[item], mt = wk_mt[item];
  int s0g = goff[g], cnt = goff[g + 1] - s0g;
  int n0 = blockIdx.x * BN;
  const short* dmat = Wtd + (size_t)g * MATSZ;

  __shared__ __align__(16) short lds[2][8192];    // 32 KB

  int tid = threadIdx.x, lane = tid & 63, w = tid >> 6;
  int wr = w >> 1, wc = w & 1;
  int lr = lane & 15, lgq = lane >> 4;
  int s0 = s0g + mt * BM;

  const short* sp[4];
  int ldst[4];
#pragma unroll
  for (int q = 0; q < 4; ++q) {
    int c = w * 4 + q;
    ldst[q] = c * 512;
    int rl = (c & 7) * 8 + (lane >> 3);
    int u = (lane & 7) ^ (rl & 7);
    if (c < 8) {
      int slot = (mt * BM + rl < cnt) ? s0 + rl : s0;
      sp[q] = H + (size_t)slot * 512 + u * 8;
    } else {
      sp[q] = dmat + (size_t)(n0 + rl) * 512 + u * 8;
    }
  }

  f32x4 acc[2][2];
#pragma unroll
  for (int i = 0; i < 2; ++i)
#pragma unroll
    for (int j = 0; j < 2; ++j) acc[i][j] = f32x4{0.f, 0.f, 0.f, 0.f};

  auto STAGE = [&](int b, int kt) {
#pragma unroll
    for (int q = 0; q < 4; ++q) gll16(sp[q] + kt * 64, &lds[b][ldst[q]]);
  };
  auto COMPUTE = [&](int b) {
    const short* L = lds[b];
#pragma unroll
    for (int ks = 0; ks < 2; ++ks) {
      bf16x8 af[2], bd[2];
#pragma unroll
      for (int i = 0; i < 2; ++i) {
        int row = wr * 32 + i * 16 + lr;
        af[i] = *(const bf16x8*)&L[row * 64 + (((ks * 4 + lgq) ^ (row & 7)) * 8)];
      }
#pragma unroll
      for (int j = 0; j < 2; ++j) {
        int dr = wc * 32 + j * 16 + lr;
        bd[j] = *(const bf16x8*)&L[4096 + dr * 64 + (((ks * 4 + lgq) ^ (dr & 7)) * 8)];
      }
#pragma unroll
      for (int i = 0; i < 2; ++i)
#pragma unroll
        for (int j = 0; j < 2; ++j)
          acc[i][j] = __builtin_amdgcn_mfma_f32_16x16x32_bf16(af[i], bd[j], acc[i][j], 0, 0, 0);
    }
  };

  STAGE(0, 0);
  __syncthreads();
  int b = 0;
#pragma unroll 1
  for (int kt = 0; kt < NKT; ++kt) {
    if (kt + 1 < NKT) STAGE(b ^ 1, kt + 1);
    COMPUTE(b);
    __syncthreads();
    b ^= 1;
  }

#pragma unroll
  for (int i = 0; i < 2; ++i)
#pragma unroll
    for (int r = 0; r < 4; ++r) {
      int mrow = wr * 32 + i * 16 + lgq * 4 + r;
      if (mt * BM + mrow < cnt) {
        int slot = s0 + mrow;
        float wv = bw[slot];
#pragma unroll
        for (int j = 0; j < 2; ++j) {
          int col = n0 + wc * 32 + j * 16 + lr;
          Osl[(size_t)slot * DD + col] = (short)(cvtpk(acc[i][j][r] * wv, 0.f) & 0xffffu);
        }
      }
    }
}

// ---------------- combine: out[t] = x[t] + sum over 6 routed + 2 shared slots ----
__global__ __launch_bounds__(256) void combine_k(
    const short* __restrict__ Osl, const float* __restrict__ x,
    const int* __restrict__ tslot, float* __restrict__ out) {
  int wv = threadIdx.x >> 6, lane = threadIdx.x & 63;
  int t = blockIdx.x * 4 + wv;
  int d0 = lane * 8;
  const float* xp = x + (size_t)t * DD + d0;
  f32x4 sa = *(const f32x4*)xp;
  f32x4 sb = *(const f32x4*)(xp + 4);
  int slots[8];
#pragma unroll
  for (int k = 0; k < 6; ++k) slots[k] = tslot[t * TK + k];
  slots[6] = RSLOT + t;
  slots[7] = RSLOT + N_TOK + t;
#pragma unroll
  for (int k = 0; k < 8; ++k) {
    uint4 hv = *(const uint4*)&Osl[(size_t)slots[k] * DD + d0];
    unsigned u[4] = {hv.x, hv.y, hv.z, hv.w};
#pragma unroll
    for (int q = 0; q < 4; ++q) {
      float lo = __builtin_bit_cast(float, u[q] << 16);
      float hi = __builtin_bit_cast(float, u[q] & 0xffff0000u);
      if (q < 2) { sa[q * 2] += lo; sa[q * 2 + 1] += hi; }
      else { sb[(q - 2) * 2] += lo; sb[(q - 2) * 2 + 1] += hi; }
    }
  }
  float* op = out + (size_t)t * DD + d0;
  *(f32x4*)op = sa;
  *(f32x4*)(op + 4) = sb;
}

extern "C" void kernel_launch(void* const* d_in, const int* in_sizes, int n_in,
                              void* d_out, int out_size, void* d_ws, size_t ws_size,
                              hipStream_t stream) {
  const float* x   = (const float*)d_in[0];
  const float* Wr  = (const float*)d_in[1];
  const float* sWg = (const float*)d_in[2];
  const float* sWu = (const float*)d_in[3];
  const float* sWd = (const float*)d_in[4];
  const float* Wg  = (const float*)d_in[5];
  const float* Wu  = (const float*)d_in[6];
  const float* Wd  = (const float*)d_in[7];
  float* out = (float*)d_out;

  char* wsb = (char*)d_ws;
  size_t off = 0;
  short* Wt = (short*)(wsb + off);    off += (size_t)198 * MATSZ * 2;   // 99 MB bf16
  short* H  = (short*)(wsb + off);    off += (size_t)NSLOT * FF * 2;    // 16 MB
  short* Osl = (short*)(wsb + off);   off += (size_t)NSLOT * DD * 2;    // 16 MB
  short* Xb = (short*)(wsb + off);    off += (size_t)N_TOK * DD * 2;    // 2 MB
  int*   top_i = (int*)(wsb + off);   off += (size_t)RSLOT * 4;
  float* top_w = (float*)(wsb + off); off += (size_t)RSLOT * 4;
  int*   btok = (int*)(wsb + off);    off += (size_t)NSLOT * 4;
  float* bwt  = (float*)(wsb + off);  off += (size_t)NSLOT * 4;
  int*   tslot = (int*)(wsb + off);   off += (size_t)RSLOT * 4;
  int*   cnt  = (int*)(wsb + off);    off += 256;
  int*   fill = (int*)(wsb + off);    off += 256;
  int*   goff = (int*)(wsb + off);    off += 512;
  int*   wk_g = (int*)(wsb + off);    off += MAXT * 4;
  int*   wk_mt = (int*)(wsb + off);   off += MAXT * 4;
  int*   nitems = (int*)(wsb + off);  off += 256;

  const short* Wtg = Wt;
  const short* Wtu = Wt + (size_t)66 * MATSZ;
  const short* Wtd = Wt + (size_t)132 * MATSZ;

  hipMemsetAsync(cnt, 0, 256, stream);
  convw_k<<<dim3(128, 198), 256, 0, stream>>>(Wg, Wu, Wd, sWg, sWu, sWd, Wt);
  convx_k<<<512, 256, 0, stream>>>(x, Xb);
  router_k<<<N_TOK / 16, 256, 0, stream>>>(x, Wr, top_i, top_w, cnt);
  offsets_k<<<1, 64, 0, stream>>>(cnt, goff, fill, wk_g, wk_mt, nitems);
  scatter_k<<<NSLOT / 256, 256, 0, stream>>>(top_i, top_w, goff, fill, btok, bwt, tslot);
  dim3 grid1(FF / BN, MAXT, 1);
  gemm1_k<<<grid1, 256, 0, stream>>>(Xb, Wtg, Wtu, goff, btok, wk_g, wk_mt, nitems, H);
  dim3 grid2(DD / BN, MAXT, 1);
  gemm2_k<<<grid2, 256, 0, stream>>>(H, Wtd, goff, bwt, wk_g, wk_mt, nitems, Osl);
  combine_k<<<N_TOK / 4, 256, 0, stream>>>(Osl, x, tslot, out);
}